// Round 8
// baseline (1546.577 us; speedup 1.0000x reference)
//
#include <hip/hip_runtime.h>
#include <cstddef>

#define NXS 64
#define NUS 32
#define NYS 32
#define NWS 64
#define BBATCH 256
#define TT  2048

// ws layout: G[160][192] col-major-by-output: G[c*192 + k]
//   cols c: [0,64) w'(tanh applied), [64,128) x', [128,160) y
//   dims k: [0,64) x, [64,128) w, [128,160) u_t, [160,192) u_{t+1}
// Setup staging: Yinv lives at ws+24576 (y-col region) between setup_inv and
// setup_gxw; setup_y overwrites it last.  Total ws use: 30720 floats.
#define WS_YSTG 24576

typedef float v2f __attribute__((ext_vector_type(2)));

__device__ __forceinline__ float fast_tanh(float x) {
    float e = __expf(2.0f * x);
    return 1.0f - 2.0f * __builtin_amdgcn_rcpf(e + 1.0f);
}

template<int CTRL>
__device__ __forceinline__ float dpp_add(float v) {
    int t = __builtin_amdgcn_update_dpp(0, __float_as_int(v), CTRL, 0xF, 0xF, true);
    return v + __int_as_float(t);
}

// packed fp32 FMA (VOP3P, CDNA2+): acc.lo += x.lo*w.lo ; acc.hi += x.hi*w.hi
__device__ __forceinline__ void pk_fma(v2f& acc, v2f x, v2f w) {
    asm("v_pk_fma_f32 %0, %1, %2, %0" : "+v"(acc) : "v"(x), "v"(w));
}

// barrier draining only LDS (global loads/stores stay in flight)
__device__ __forceinline__ void step_barrier() {
    asm volatile("s_waitcnt lgkmcnt(0)\n\ts_barrier" ::: "memory");
}

// ---------------------------------------------------------------------------
// setup 1/3: Gauss-Jordan Yinv -> ws[WS_YSTG .. +4096)   (1 block)
__global__ __launch_bounds__(1024) void setup_inv_kernel(const float* __restrict__ Y,
                                                         float* __restrict__ ws) {
    __shared__ float M[64 * 129];
    __shared__ float rowk[128];
    __shared__ float ck[64];
    const int tid = threadIdx.x;

    for (int idx = tid; idx < 64 * 64; idx += 1024) {
        int r = idx >> 6, c = idx & 63;
        M[r * 129 + c]      = Y[idx];
        M[r * 129 + 64 + c] = (r == c) ? 1.0f : 0.0f;
    }
    __syncthreads();

    for (int k = 0; k < 64; ++k) {
        float dv = 1.0f / M[k * 129 + k];
        if (tid < 128) rowk[tid] = M[k * 129 + tid] * dv;
        if (tid >= 128 && tid < 192) ck[tid - 128] = M[(tid - 128) * 129 + k];
        __syncthreads();
        for (int idx = tid; idx < 64 * 128; idx += 1024) {
            int r = idx >> 7, c = idx & 127;
            float cur = M[r * 129 + c];
            M[r * 129 + c] = (r == k) ? rowk[c] : cur - ck[r] * rowk[c];
        }
        __syncthreads();
    }
    for (int idx = tid; idx < 4096; idx += 1024) {
        int r = idx >> 6, c = idx & 63;
        ws[WS_YSTG + idx] = M[r * 129 + 64 + c];
    }
}

// ---------------------------------------------------------------------------
// setup 2/3: per-block WxT=[A;B1;B2]~@Yinv in LDS, then write w-cols+x-cols
// of G (24576 floats split over 16 blocks).
__global__ __launch_bounds__(256) void setup_gxw_kernel(const float* __restrict__ lam,
                                                        const float* __restrict__ A,
                                                        const float* __restrict__ B1,
                                                        const float* __restrict__ B2,
                                                        const float* __restrict__ C2,
                                                        const float* __restrict__ D21,
                                                        float* __restrict__ ws) {
    __shared__ float Yi[64 * 64];
    __shared__ float WxT[160 * 64];
    const int tid = threadIdx.x;
    const int bid = blockIdx.x;

    for (int idx = tid; idx < 4096; idx += 256) Yi[idx] = ws[WS_YSTG + idx];
    __syncthreads();

    for (int idx = tid; idx < 10240; idx += 256) {
        int k = idx >> 6, j = idx & 63;
        float s = 0.0f;
        if (k < 64) {
            #pragma unroll 8
            for (int m = 0; m < 64; ++m) s += A[m * 64 + k] * Yi[m * 64 + j];
        } else if (k < 96) {
            int ku = k - 64;
            #pragma unroll 8
            for (int m = 0; m < 64; ++m) s += B1[m * 32 + ku] * Yi[m * 64 + j];
        } else {
            int kw = k - 96;
            #pragma unroll 8
            for (int m = 0; m < 64; ++m) s += B2[m * 64 + kw] * Yi[m * 64 + j];
        }
        WxT[idx] = s;
    }
    __syncthreads();

    // this block's slice of w-cols + x-cols: elements [bid*1536, bid*1536+1536)
    for (int idx = bid * 1536 + tid; idx < bid * 1536 + 1536; idx += 256) {
        int c = idx / 192;
        int k = idx - c * 192;
        int km = (k < 64) ? k : (k < 128) ? (96 + k - 64) : (64 + k - 128);
        float v;
        if (c < 64) {                         // w'-col
            if (k < 160) {
                float s = 0.0f;
                #pragma unroll 8
                for (int m = 0; m < 64; ++m) s += WxT[km * 64 + m] * C2[c * 64 + m];
                v = s / lam[c];
            } else {
                v = D21[c * 32 + (k - 160)] / lam[c];
            }
        } else {                              // x'-col
            int j = c - 64;
            v = (k < 160) ? WxT[km * 64 + j] : 0.0f;
        }
        ws[c * 192 + k] = v;
    }
}

// ---------------------------------------------------------------------------
// setup 3/3: y-cols (no Yinv needed) — overwrites the staging region, runs last.
__global__ __launch_bounds__(256) void setup_y_kernel(const float* __restrict__ C1,
                                                      const float* __restrict__ D11,
                                                      const float* __restrict__ D12,
                                                      float* __restrict__ ws) {
    for (int idx = blockIdx.x * 256 + threadIdx.x; idx < 6144; idx += 16 * 256) {
        int c = 128 + idx / 192;
        int k = idx % 192;
        int j = c - 128;
        float v = (k < 64)  ? C1[j * 64 + k]
                : (k < 128) ? D12[j * 64 + (k - 64)]
                : (k < 160) ? D11[j * 32 + (k - 128)]
                            : 0.0f;
        ws[c * 192 + k] = v;
    }
}

// ---------------------------------------------------------------------------
// Scan v8: TWO chains per 1024-thread block (grid 128), wave-separated:
// waves 0-7 = chain A (v7's 512-lane partition verbatim), waves 8-15 = chain
// B.  4 waves/SIMD (2 per chain, auto-balanced 3-out/2-out) -> per-SIMD issue
// serves two chain-steps; exposed latency shrinks from 41% to ~20% of step.
// Per-chain partition: 64 groups x 8 lanes; group Gq computes w[Gq] (e==0
// writes tanh) and x[Gq] (e==1 writes); Gq<32 also y[Gq] (e==2 batches).
// K-split 8, SLP=20 banking, 36-pad u ring, 16-step prefetch (all v6/v7-
// verified).  New trims: u-fragment pre-read BEFORE the barrier (compiler
// can't hoist across the asm barrier itself); accumulator split 6+6.
__global__ __launch_bounds__(1024, 4) void rnn8_kernel(const float* __restrict__ xp,
                                                       const float* __restrict__ ws,
                                                       float* __restrict__ out) {
    const int tid = threadIdx.x;
    const int ch  = tid >> 9;                      // chain within block
    const int t   = tid & 511;                     // v7-tid within chain
    const int b   = blockIdx.x * 2 + ch;

    __shared__ __align__(16) float sbuf[2][2][160];   // [chain][pp][dim]
    __shared__ __align__(16) float uRs[2][32][36];    // [chain][slot][dim]

    const float4* __restrict__ xp4 = (const float4*)(xp + (size_t)b * (TT * NUS));
    const size_t yb   = (size_t)b * (TT * NYS);
    const size_t xoff = (size_t)BBATCH * TT * NYS;

    // ---- init: u slots 0..30 = u_0..30, slot 31 = 0 (u_{-1}); sbuf[ch][0]=0 --
    if (t < 256) {
        int s = t >> 3, q8 = t & 7;
        float4 v = make_float4(0.f, 0.f, 0.f, 0.f);
        if (s < 31) v = xp4[s * 8 + q8];
        *(float4*)&uRs[ch][s][q8 * 4] = v;
    }
    if (t < 160) sbuf[ch][0][t] = 0.0f;
    __syncthreads();

    const int e  = t & 7;
    const int Gq = t >> 3;                         // [0,64)

    // ---- weights: NOUT outputs x 12 v2f (8 state + 4 u) ----
    const int NOUT = (Gq < 32) ? 3 : 2;            // wave-uniform
    v2f w[3][12];
    #pragma unroll
    for (int r = 0; r < 3; ++r) {
        if (r >= NOUT) break;
        const int col = (r == 0) ? Gq : (r == 1) ? (64 + Gq) : (128 + Gq);
        const float* Gc = ws + (size_t)col * 192;
        const float* sb = Gc + 16 * e;
        #pragma unroll
        for (int k = 0; k < 4; ++k) {
            float4 gv = *(const float4*)(sb + 4 * k);
            w[r][2 * k]     = (v2f){gv.x, gv.y};
            w[r][2 * k + 1] = (v2f){gv.z, gv.w};
        }
        const float* ub = Gc + ((e < 4) ? (128 + 8 * e) : (160 + 8 * (e - 4)));
        #pragma unroll
        for (int tt = 0; tt < 2; ++tt) {
            float4 gv = *(const float4*)(ub + 4 * tt);
            w[r][8 + 2 * tt] = (v2f){gv.x, gv.y};
            w[r][9 + 2 * tt] = (v2f){gv.z, gv.w};
        }
    }

    const int wr_off = (e == 0) ? (((64 + Gq) >> 4) * 20 + ((64 + Gq) & 15))
                                : ((Gq >> 4) * 20 + (Gq & 15));

    float ybat[8];
    float lastx = 0.0f;
    float4 upref = make_float4(0.f, 0.f, 0.f, 0.f);
    float4 u0r, u1r;                               // pre-read u fragment

    auto uread = [&](int ip, int ic) {
        const float4* uu = (const float4*)&uRs[ch][(e < 4) ? ip : ic][8 * (e & 3)];
        u0r = uu[0]; u1r = uu[1];
    };

    auto dostep = [&](int rb, int wb, float& s0o, float& s1o, float& s2o) {
        const float4* sv4 = (const float4*)(&sbuf[ch][rb][0] + e * 20);
        float4 s0 = sv4[0], s1 = sv4[1], s2 = sv4[2], s3 = sv4[3];
        v2f sv[12] = {{s0.x, s0.y}, {s0.z, s0.w}, {s1.x, s1.y}, {s1.z, s1.w},
                      {s2.x, s2.y}, {s2.z, s2.w}, {s3.x, s3.y}, {s3.z, s3.w},
                      {u0r.x, u0r.y}, {u0r.z, u0r.w}, {u1r.x, u1r.y}, {u1r.z, u1r.w}};
        float sr[3] = {0.f, 0.f, 0.f};
        #pragma unroll
        for (int r = 0; r < 3; ++r) {
            if (r >= NOUT) break;
            v2f acc = (v2f){0.f, 0.f}, acc2 = (v2f){0.f, 0.f};
            #pragma unroll
            for (int k = 0; k < 6; ++k)  pk_fma(acc,  sv[k],     w[r][k]);
            #pragma unroll
            for (int k = 0; k < 6; ++k)  pk_fma(acc2, sv[6 + k], w[r][6 + k]);
            v2f a = acc + acc2;
            float s = a.x + a.y;
            s = dpp_add<0xB1>(s);      // xor1
            s = dpp_add<0x4E>(s);      // xor2
            s = dpp_add<0x141>(s);     // row_half_mirror -> 8-lane all-sum
            sr[r] = s;
        }
        if (e < 2) {
            float val = (e == 0) ? fast_tanh(sr[0]) : sr[1];
            sbuf[ch][wb][wr_off] = val;
        }
        s0o = sr[0]; s1o = sr[1]; s2o = sr[2];
    };

    // ---- prologue: S_0 from zero state; u_t = slot31(0), u_{t+1} = u_0 ----
    {
        uread(31, 0);
        float a, bv, c;
        dostep(0, 1, a, bv, c);
        uread(0, 1);                               // pre-read for step 0
    }
    step_barrier();

    #pragma unroll 8
    for (int i = 0; i < TT; ++i) {
        const int rp = (i + 1) & 1, wp = i & 1;
        if ((i & 15) == 0) {                   // issue loads for u_{i+16..i+31}
            int tt = i + 16 + (t >> 3);
            if (t < 128 && tt < TT) upref = xp4[tt * 8 + (t & 7)];
        }
        if ((i & 15) == 8) {                   // land u_{i+8..i+23}
            int tt = i + 8 + (t >> 3);
            if (t < 128 && tt < TT) *(float4*)&uRs[ch][tt & 31][(t & 7) * 4] = upref;
        }
        float sr0, sr1, sr2;
        dostep(rp, wp, sr0, sr1, sr2);
        lastx = sr1;
        if (NOUT == 3 && e == 2) {
            ybat[i & 7] = sr2;
            if ((i & 7) == 7) {
                size_t base = yb + (size_t)(i - 7) * NYS + Gq;
                #pragma unroll
                for (int ss = 0; ss < 8; ++ss) out[base + (size_t)ss * NYS] = ybat[ss];
            }
        }
        uread((i + 1) & 31, (i + 2) & 31);     // pre-read u for step i+1
        step_barrier();
    }

    // ---- epilogue: x_final = x_{TT} (computed at i = TT-1) ----
    if (e == 1) out[xoff + (size_t)b * 64 + Gq] = lastx;
}

// ---------------------------------------------------------------------------
extern "C" void kernel_launch(void* const* d_in, const int* in_sizes, int n_in,
                              void* d_out, int out_size, void* d_ws, size_t ws_size,
                              hipStream_t stream) {
    const float* xp  = (const float*)d_in[0];
    const float* Y   = (const float*)d_in[1];
    const float* lam = (const float*)d_in[2];
    const float* A   = (const float*)d_in[3];
    const float* B1  = (const float*)d_in[4];
    const float* B2  = (const float*)d_in[5];
    const float* C1  = (const float*)d_in[6];
    const float* D11 = (const float*)d_in[7];
    const float* D12 = (const float*)d_in[8];
    const float* C2  = (const float*)d_in[9];
    const float* D21 = (const float*)d_in[10];
    float* out = (float*)d_out;
    float* ws  = (float*)d_ws;

    hipLaunchKernelGGL(setup_inv_kernel, dim3(1),  dim3(1024), 0, stream, Y, ws);
    hipLaunchKernelGGL(setup_gxw_kernel, dim3(16), dim3(256),  0, stream,
                       lam, A, B1, B2, C2, D21, ws);
    hipLaunchKernelGGL(setup_y_kernel,   dim3(16), dim3(256),  0, stream,
                       C1, D11, D12, ws);
    hipLaunchKernelGGL(rnn8_kernel, dim3(BBATCH / 2), dim3(1024), 0, stream,
                       xp, ws, out);
}